// Round 17
// baseline (61.851 us; speedup 1.0000x reference)
//
#include <hip/hip_runtime.h>

#define NB 8
#define SL 128
#define HD 768
#define HDU (HD / 4)     // 192 uints per fp8 row
#define NCHK 8           // h-chunks of 96 elems (24 dwords, 96 B)
#define CHKD 24          // dwords per chunk-row
#define LPAD 160         // padded compact-list length (8 iters x 20 entries)

typedef float v2f __attribute__((ext_vector_type(2)));

// Kernel 1: blocks [0,1024): per-(b,i) pack -> hidden (f32) + keyemb (fp8).
// blocks [1024,4096): convert W_val f32 -> fp8, CHUNK-MAJOR layout
//   wv8c[c][row][24 dwords], c = h/96. blocks [4096,4102): zero avg accums.
__global__ __launch_bounds__(256) void k_prep(
    const float* __restrict__ seq,
    const float* __restrict__ W_key,
    const float* __restrict__ W_val,
    const int* __restrict__ valid,
    const int* __restrict__ kvidx,
    const int* __restrict__ aspect,
    float* __restrict__ hidden,
    unsigned int* __restrict__ keyemb,
    unsigned int* __restrict__ wv8c,
    unsigned int* __restrict__ avg_zero) {
  int blk = blockIdx.x;
  int tid = threadIdx.x;

  if (blk >= NB * SL + 3072) {
    int base = (blk - NB * SL - 3072) * 2048 + tid;
#pragma unroll
    for (int it = 0; it < 8; ++it) avg_zero[base + 256 * it] = 0u;
    return;
  }
  if (blk >= NB * SL) {
    // W_val conversion to chunk-major fp8: D = 4-elem group index.
    int cb = blk - NB * SL;
    const float4* src = (const float4*)W_val;
    int base = cb * 1024 + tid;
#pragma unroll
    for (int it = 0; it < 4; ++it) {
      int D = base + 256 * it;
      float4 v = src[D];                 // coalesced read
      int r = D / 192;                   // row
      int d = D - r * 192;               // dword-group in row
      int c = d / CHKD;                  // chunk
      int w = d - c * CHKD;              // dword within chunk-row
      int w8 = __builtin_amdgcn_cvt_pk_fp8_f32(v.x, v.y, 0, false);
      w8 = __builtin_amdgcn_cvt_pk_fp8_f32(v.z, v.w, w8, true);
      wv8c[(size_t)c * (16384 * CHKD) + r * CHKD + w] = (unsigned int)w8;
    }
    return;
  }

  int b = blk & 7;
  int i = blk >> 3;
  int bq = b * SL + i;
  int lane = tid & 63, wv = tid >> 6;

  __shared__ int s_wcnt[4];
  __shared__ int s_src;

  int v = (tid < SL) ? (valid[b * SL + tid] != 0) : 0;
  unsigned long long m = __ballot(v);
  if (lane == 0) s_wcnt[wv] = __popcll(m);
  if (tid == 0) s_src = SL;  // sentinel
  __syncthreads();
  int count = s_wcnt[0] + s_wcnt[1];
  if (v) {
    int rank = __popcll(m & ((1ull << lane) - 1ull)) + (wv == 1 ? s_wcnt[0] : 0);
    if (rank == i) s_src = tid;
  }
  __syncthreads();
  int src = s_src;

  if (tid < HD / 4) {  // 192 threads: one float4 (hidden) + one fp8x4 uint (key)
    float4 hv = make_float4(0.f, 0.f, 0.f, 0.f);
    if (i < count && src < SL) {
      float asp = (float)aspect[b * SL + i];
      const float4* srow = (const float4*)(seq + ((size_t)(b * SL + src)) * HD);
      float4 s = srow[tid];
      hv = make_float4(s.x * asp, s.y * asp, s.z * asp, s.w * asp);
    }
    ((float4*)(hidden + (size_t)bq * HD))[tid] = hv;

    int id = kvidx[b * SL + i];
    unsigned int kb = 0;  // fp8 zero
    if (id != 0) {
      float4 kv = ((const float4*)(W_key + (size_t)id * HD))[tid];
      int w = __builtin_amdgcn_cvt_pk_fp8_f32(kv.x, kv.y, 0, false);
      w = __builtin_amdgcn_cvt_pk_fp8_f32(kv.z, kv.w, w, true);
      kb = (unsigned int)w;
    }
    keyemb[(size_t)bq * HDU + tid] = kb;
  }
}

// Kernel 2: per (b,q): QK (fp8 keys, hidden in regs) -> masked softmax ->
// compact surviving (p,f) -> write zero-padded lists for k_gather.
// blockIdx % 8 == b pins each batch to one XCD (keyemb panel L2-local).
__global__ __launch_bounds__(512) void k_qk(
    const float* __restrict__ hidden,
    const unsigned int* __restrict__ keyemb,
    const int* __restrict__ features,
    const int* __restrict__ pos,
    float* __restrict__ pc_out,
    int* __restrict__ fc_out,
    int* __restrict__ mcount) {
  int blk = blockIdx.x;
  int b = blk & 7;
  int q = blk >> 3;
  int bq = b * SL + q;
  int tid = threadIdx.x;
  int wave = tid >> 6, lane = tid & 63;

  __shared__ float s_p[SL];
  __shared__ int s_f[SL];
  __shared__ float s_pc[LPAD];
  __shared__ int s_fc[LPAD];
  __shared__ float s_sum;
  __shared__ int s_cnt2[2];
  __shared__ int s_m;

  if (tid < LPAD) {  // zero-pad compact lists
    s_pc[tid] = 0.f;
    s_fc[tid] = 0;
  }

  // hidden row into registers (each wave holds the full row, float4 layout)
  float4 hreg[3];
  {
    const float4* h4 = (const float4*)(hidden + (size_t)bq * HD);
#pragma unroll
    for (int j = 0; j < 3; ++j) hreg[j] = h4[lane + 64 * j];
  }
  if (tid < SL) s_f[tid] = features[(size_t)bq * SL + tid];

  const float rscale = 0.03608439182435161f;  // 1/sqrt(768)
  for (int k = wave; k < SL; k += 8) {
    const unsigned int* kr = keyemb + (size_t)(b * SL + k) * HDU;
    float part = 0.f;
#pragma unroll
    for (int j = 0; j < 3; ++j) {
      unsigned int kv = kr[lane + 64 * j];  // 4 fp8 elems
      float4 h = hreg[j];
      v2f p0 = __builtin_amdgcn_cvt_pk_f32_fp8(kv, false);
      v2f p1 = __builtin_amdgcn_cvt_pk_f32_fp8(kv, true);
      part += p0.x * h.x + p0.y * h.y + p1.x * h.z + p1.y * h.w;
    }
#pragma unroll
    for (int off = 32; off; off >>= 1) part += __shfl_xor(part, off);
    if (lane == 0) s_p[k] = part * rscale;
  }
  __syncthreads();
  if (tid < SL) {
    float d = (pos[(size_t)bq * SL + tid] != 0) ? expf(s_p[tid]) : 0.f;
    s_p[tid] = d;
  }
  __syncthreads();
  if (tid < 64) {  // wave 0 tree-reduces the denominator
    float part = s_p[tid] + s_p[tid + 64];
#pragma unroll
    for (int off = 32; off; off >>= 1) part += __shfl_xor(part, off);
    if (tid == 0) s_sum = part + 1e-10f;
  }
  __syncthreads();

  // compact surviving (p, f) pairs
  int keep = 0;
  float pv = 0.f;
  int fv = 0;
  if (tid < SL) {
    pv = s_p[tid] / s_sum;
    fv = s_f[tid];
    keep = (pv != 0.f) && (fv != 0);
  }
  unsigned long long km = __ballot(keep);
  if (lane == 0 && wave < 2) s_cnt2[wave] = __popcll(km);
  __syncthreads();
  if (keep) {
    int rank = __popcll(km & ((1ull << lane) - 1ull)) + (wave == 1 ? s_cnt2[0] : 0);
    s_pc[rank] = pv;
    s_fc[rank] = fv;
  }
  if (tid == 0) s_m = s_cnt2[0] + s_cnt2[1];
  __syncthreads();

  if (tid < LPAD) {
    pc_out[(size_t)bq * LPAD + tid] = s_pc[tid];
    fc_out[(size_t)bq * LPAD + tid] = s_fc[tid];
  }
  if (tid == 0) mcount[bq] = s_m;
}

// Kernel 3: h-chunked gather. Block = (chunk c = blk&7 -> XCD pin, bq = blk>>3).
// Each XCD's working set = one 1.5 MB chunk-table -> fully L2-resident.
// 4 waves x 5 entry-slots x 12 lanes (uint2 = 8 fp8 elems per lane).
__global__ __launch_bounds__(256) void k_gather(
    const float* __restrict__ pc_in,
    const int* __restrict__ fc_in,
    const int* __restrict__ mcount,
    const unsigned int* __restrict__ wv8c,
    float* __restrict__ avg_sum,
    int* __restrict__ avg_cnt) {
  int blk = blockIdx.x;
  int c = blk & 7;
  int bq = blk >> 3;
  int b = bq >> 7;
  int tid = threadIdx.x;
  int wave = tid >> 6, lane = tid & 63;

  __shared__ float s_pc[LPAD];
  __shared__ int s_fc[LPAD];
  __shared__ float s_red[20][96];
  __shared__ int s_m;

  if (tid < LPAD) {
    s_pc[tid] = pc_in[(size_t)bq * LPAD + tid];
    s_fc[tid] = fc_in[(size_t)bq * LPAD + tid];
  }
  if (tid == 0) s_m = mcount[bq];
  __syncthreads();
  int m = s_m;
  int niter = (m + 19) / 20;

  int slot = lane / 12;            // 0..4 active, slot 5 (lanes 60-63) idle
  int j = lane - slot * 12;        // uint2 index within chunk-row
  bool active = (slot < 5);

  float acc[8];
#pragma unroll
  for (int i = 0; i < 8; ++i) acc[i] = 0.f;

  const unsigned int* tbl = wv8c + (size_t)c * (16384 * CHKD);
  for (int it = 0; it < niter; ++it) {
    int e = it * 20 + wave * 5 + (active ? slot : 0);
    float p = s_pc[e];
    int f = s_fc[e];
    if (active) {
      uint2 v = *(const uint2*)(tbl + (size_t)f * CHKD + 2 * j);
      v2f p0 = __builtin_amdgcn_cvt_pk_f32_fp8(v.x, false);
      v2f p1 = __builtin_amdgcn_cvt_pk_f32_fp8(v.x, true);
      v2f p2 = __builtin_amdgcn_cvt_pk_f32_fp8(v.y, false);
      v2f p3 = __builtin_amdgcn_cvt_pk_f32_fp8(v.y, true);
      acc[0] += p * p0.x; acc[1] += p * p0.y;
      acc[2] += p * p1.x; acc[3] += p * p1.y;
      acc[4] += p * p2.x; acc[5] += p * p2.y;
      acc[6] += p * p3.x; acc[7] += p * p3.y;
    }
  }
  if (active) {
    float* dst = &s_red[wave * 5 + slot][j * 8];
    ((float4*)dst)[0] = make_float4(acc[0], acc[1], acc[2], acc[3]);
    ((float4*)dst)[1] = make_float4(acc[4], acc[5], acc[6], acc[7]);
  }
  __syncthreads();

  if (tid < 96) {
    float s = 0.f;
#pragma unroll
    for (int t = 0; t < 20; ++t) s += s_red[t][tid];
    size_t idx = (size_t)b * HD + c * 96 + tid;
    atomicAdd(&avg_sum[idx], s);
    atomicAdd(&avg_cnt[idx], (s != 0.f) ? 1 : 0);
  }
}

// Kernel 4: avg = sum/cnt; logits = [pooled, avg] @ W_dense^T + b_dense
__global__ __launch_bounds__(192) void k_dense(
    const float* __restrict__ pooled,
    const float* __restrict__ avg_sum,
    const int* __restrict__ avg_cnt,
    const float* __restrict__ W_dense,
    const float* __restrict__ b_dense,
    float* __restrict__ out) {
  int b = blockIdx.x;
  int tid = threadIdx.x;
  __shared__ float s_avg[HD];
  for (int c = tid; c < HD; c += 192)
    s_avg[c] = avg_sum[(size_t)b * HD + c] / (float)avg_cnt[(size_t)b * HD + c];
  __syncthreads();
  int n = tid >> 6, lane = tid & 63;
  float part = 0.f;
  for (int j = lane; j < HD; j += 64)
    part += pooled[(size_t)b * HD + j] * W_dense[(size_t)n * (2 * HD) + j];
  for (int j = lane; j < HD; j += 64)
    part += s_avg[j] * W_dense[(size_t)n * (2 * HD) + HD + j];
#pragma unroll
  for (int off = 32; off; off >>= 1) part += __shfl_xor(part, off);
  if (lane == 0) out[b * 3 + n] = part + b_dense[n];
}

extern "C" void kernel_launch(void* const* d_in, const int* in_sizes, int n_in,
                              void* d_out, int out_size, void* d_ws, size_t ws_size,
                              hipStream_t stream) {
  const float* seq     = (const float*)d_in[0];
  const float* pooled  = (const float*)d_in[1];
  const float* W_key   = (const float*)d_in[2];
  const float* W_val   = (const float*)d_in[3];
  const float* W_dense = (const float*)d_in[4];
  const float* b_dense = (const float*)d_in[5];
  const int* valid     = (const int*)d_in[6];
  const int* kvidx     = (const int*)d_in[7];
  const int* features  = (const int*)d_in[8];
  const int* pos       = (const int*)d_in[9];
  const int* aspect    = (const int*)d_in[10];
  float* out = (float*)d_out;

  float* hidden = (float*)d_ws;                                 // [B,L,H] f32
  unsigned int* keyemb =
      (unsigned int*)(hidden + (size_t)NB * SL * HD);           // [B,L,H] fp8
  float* avg_sum = (float*)(keyemb + (size_t)NB * SL * HDU);    // [B,H] f32
  int* avg_cnt = (int*)(avg_sum + (size_t)NB * HD);             // [B,H] i32
  float* pc = (float*)(avg_cnt + (size_t)NB * HD);              // [1024,160] f32
  int* fc = (int*)(pc + (size_t)NB * SL * LPAD);                // [1024,160] i32
  int* mcount = fc + (size_t)NB * SL * LPAD;                    // [1024] i32
  unsigned int* wv8c = (unsigned int*)(mcount + NB * SL);       // [8][16384][24] fp8

  k_prep<<<NB * SL + 3072 + 6, 256, 0, stream>>>(
      seq, W_key, W_val, valid, kvidx, aspect, hidden, keyemb, wv8c,
      (unsigned int*)avg_sum);
  k_qk<<<NB * SL, 512, 0, stream>>>(hidden, keyemb, features, pos, pc, fc, mcount);
  k_gather<<<NB * SL * NCHK, 256, 0, stream>>>(pc, fc, mcount, wv8c, avg_sum, avg_cnt);
  k_dense<<<NB, 192, 0, stream>>>(pooled, avg_sum, avg_cnt, W_dense, b_dense, out);
}